// Round 3
// baseline (530.700 us; speedup 1.0000x reference)
//
#include <hip/hip_runtime.h>

typedef __attribute__((ext_vector_type(8))) _Float16 half8;
typedef __attribute__((ext_vector_type(4))) _Float16 half4v;
typedef __attribute__((ext_vector_type(4))) float f32x4;

__device__ __forceinline__ void gll16(const void* g, void* l) {
  __builtin_amdgcn_global_load_lds(
      (const __attribute__((address_space(1))) unsigned int*)g,
      (__attribute__((address_space(3))) unsigned int*)l, 16, 0, 0);
}

__device__ __forceinline__ float h2f(unsigned short hb) {
  _Float16 h;
  __builtin_memcpy(&h, &hb, 2);
  return (float)h;
}

// ---------------- LayerNorm + fp16 cast: one block per row of C=1024 ----------------
__global__ __launch_bounds__(256) void ln_cast_f16(
    const float* __restrict__ x, const float* __restrict__ g,
    const float* __restrict__ b, _Float16* __restrict__ y) {
  const int C = 1024;
  size_t row = blockIdx.x;
  int t = threadIdx.x;
  const float4* xr = (const float4*)(x + row * C);
  float4 v = xr[t];
  float s = v.x + v.y + v.z + v.w;
  float s2 = v.x * v.x + v.y * v.y + v.z * v.z + v.w * v.w;
#pragma unroll
  for (int off = 1; off < 64; off <<= 1) {
    s += __shfl_xor(s, off, 64);
    s2 += __shfl_xor(s2, off, 64);
  }
  __shared__ float ps[4], ps2[4];
  int wave = t >> 6, lane = t & 63;
  if (lane == 0) { ps[wave] = s; ps2[wave] = s2; }
  __syncthreads();
  s = ps[0] + ps[1] + ps[2] + ps[3];
  s2 = ps2[0] + ps2[1] + ps2[2] + ps2[3];
  float mu = s * (1.0f / C);
  float var = s2 * (1.0f / C) - mu * mu;
  float rstd = rsqrtf(var + 1e-5f);
  float4 gv = ((const float4*)g)[t];
  float4 bv = ((const float4*)b)[t];
  half4v o;
  o.x = (_Float16)((v.x - mu) * rstd * gv.x + bv.x);
  o.y = (_Float16)((v.y - mu) * rstd * gv.y + bv.y);
  o.z = (_Float16)((v.z - mu) * rstd * gv.z + bv.z);
  o.w = (_Float16)((v.w - mu) * rstd * gv.w + bv.w);
  ((half4v*)(y + row * C))[t] = o;
}

// ------------- LayerNorm + int8 quant (per-row scale): one block per row -------------
__global__ __launch_bounds__(256) void ln_cast_i8(
    const float* __restrict__ x, const float* __restrict__ g,
    const float* __restrict__ b, char* __restrict__ y,
    float* __restrict__ yscale) {
  const int C = 1024;
  size_t row = blockIdx.x;
  int t = threadIdx.x;
  const float4* xr = (const float4*)(x + row * C);
  float4 v = xr[t];
  float s = v.x + v.y + v.z + v.w;
  float s2 = v.x * v.x + v.y * v.y + v.z * v.z + v.w * v.w;
#pragma unroll
  for (int off = 1; off < 64; off <<= 1) {
    s += __shfl_xor(s, off, 64);
    s2 += __shfl_xor(s2, off, 64);
  }
  __shared__ float ps[4], ps2[4], pm[4];
  int wave = t >> 6, lane = t & 63;
  if (lane == 0) { ps[wave] = s; ps2[wave] = s2; }
  __syncthreads();
  s = ps[0] + ps[1] + ps[2] + ps[3];
  s2 = ps2[0] + ps2[1] + ps2[2] + ps2[3];
  float mu = s * (1.0f / C);
  float var = s2 * (1.0f / C) - mu * mu;
  float rstd = rsqrtf(var + 1e-5f);
  float4 gv = ((const float4*)g)[t];
  float4 bv = ((const float4*)b)[t];
  float o0 = (v.x - mu) * rstd * gv.x + bv.x;
  float o1 = (v.y - mu) * rstd * gv.y + bv.y;
  float o2 = (v.z - mu) * rstd * gv.z + bv.z;
  float o3 = (v.w - mu) * rstd * gv.w + bv.w;
  float mx = fmaxf(fmaxf(fabsf(o0), fabsf(o1)), fmaxf(fabsf(o2), fabsf(o3)));
#pragma unroll
  for (int off = 1; off < 64; off <<= 1) mx = fmaxf(mx, __shfl_xor(mx, off, 64));
  if (lane == 0) pm[wave] = mx;
  __syncthreads();
  mx = fmaxf(fmaxf(pm[0], pm[1]), fmaxf(pm[2], pm[3]));
  mx = fmaxf(mx, 1e-20f);
  float inv = 127.0f / mx;
  int q0 = (int)rintf(o0 * inv), q1 = (int)rintf(o1 * inv);
  int q2 = (int)rintf(o2 * inv), q3 = (int)rintf(o3 * inv);
  unsigned pk = ((unsigned)(q0 & 0xff)) | ((unsigned)(q1 & 0xff) << 8) |
                ((unsigned)(q2 & 0xff) << 16) | ((unsigned)(q3 & 0xff) << 24);
  ((unsigned*)(y + row * C))[t] = pk;
  if (t == 0) yscale[row] = mx * (1.0f / 127.0f);
}

// -------- QK^T GEMM, 256x256 tile, 8-phase schedule: S = fp16((q.k/32)*c[x]) --------
// RESUBMISSION of round-2 kernel (bench infra failed; schedule re-audited:
// uniform control flow, vmcnt ledger balanced, WAR protected by wait+barrier,
// addressing bounded, fragment maps identical to round-0 verified kernel).
// 512 thr = 8 waves (2M x 4N), per-wave 128x64 via mfma_f32_16x16x32_f16.
// BK=64, double-buffered LDS (2 x 32KB per operand = 128 KiB). 4 phases per
// K-tile: phase = {ds_read 4-8 x b128 | stage one K-half (4 gll16) | barrier |
// 16 MFMA with setprio | barrier}. Counted vmcnt(4) at end of P2/P4 retires
// loads issued 3 phases earlier -- never vmcnt(0) in steady state (T3+T4+T5).
// LDS chunk-major [chunk][row][8]: gll16-linear, measured 0 bank conflicts.
__global__ __launch_bounds__(512, 2) void gemm_qk_8ph(
    const _Float16* __restrict__ A,   // [B][1024][1024] q16
    const _Float16* __restrict__ Bm,  // [B][8192][1024] k16
    _Float16* __restrict__ Sm,        // [B][1024][8192]
    const float* __restrict__ conf)   // [B][8192]
{
  const int N = 8192, K = 1024;
  int bz = blockIdx.z;
  const _Float16* Ab = A + (size_t)bz * 1024 * K;
  const _Float16* Bb = Bm + (size_t)bz * (size_t)N * K;
  _Float16* Sb = Sm + (size_t)bz * 1024 * N;

  // per operand: 2 buf x 8 chunks x 256 rows x 8 halfs = 64 KB
  __shared__ _Float16 lA[2 * 16384];
  __shared__ _Float16 lB[2 * 16384];

  int tid = threadIdx.x;
  int wave = tid >> 6, lane = tid & 63;
  int wm = wave >> 2, wn = wave & 3;   // 2 x 4 wave grid
  int lr16 = lane & 15, lq = lane >> 4;
  int m0 = blockIdx.y * 256, n0 = blockIdx.x * 256;

  f32x4 acc[8][4];
#pragma unroll
  for (int i = 0; i < 8; ++i)
#pragma unroll
    for (int j = 0; j < 4; ++j) {
      f32x4 z = {0.f, 0.f, 0.f, 0.f};
      acc[i][j] = z;
    }
  half8 bfr[4];

  // staging: thread (r, c0) owns row r, chunks {c0, c0+2} of each K-half,
  // for both A and B. One stage_half = 4 gll16 = one 32KB K-half of the tile.
  int r = tid & 255, c0 = tid >> 8;
  const _Float16* gA = Ab + (size_t)(m0 + r) * K;
  const _Float16* gB = Bb + (size_t)(n0 + r) * K;
  int ldst = r * 8;

  auto stage_half = [&](int t, int h) {
    int kb = t * 64 + h * 32;
    int bo = (t & 1) * 16384;
#pragma unroll
    for (int j = 0; j < 2; ++j) {
      int c = c0 + 2 * j;
      gll16(gA + kb + c * 8, &lA[bo + (h * 4 + c) * 2048 + ldst]);
      gll16(gB + kb + c * 8, &lB[bo + (h * 4 + c) * 2048 + ldst]);
    }
  };

#define DO_PHASE(BO, MH, KS, READB, STAGE_STMT, WAIT_STMT)                        \
  {                                                                               \
    __builtin_amdgcn_sched_barrier(0);                                            \
    const _Float16* la_ =                                                         \
        &lA[(BO) + ((KS)*4 + lq) * 2048 + (wm * 128 + (MH)*64 + lr16) * 8];       \
    half8 a0_ = *(const half8*)(la_);                                             \
    half8 a1_ = *(const half8*)(la_ + 128);                                       \
    half8 a2_ = *(const half8*)(la_ + 256);                                       \
    half8 a3_ = *(const half8*)(la_ + 384);                                       \
    if (READB) {                                                                  \
      const _Float16* lb_ =                                                       \
          &lB[(BO) + ((KS)*4 + lq) * 2048 + (wn * 64 + lr16) * 8];                \
      bfr[0] = *(const half8*)(lb_);                                              \
      bfr[1] = *(const half8*)(lb_ + 128);                                        \
      bfr[2] = *(const half8*)(lb_ + 256);                                        \
      bfr[3] = *(const half8*)(lb_ + 384);                                        \
    }                                                                             \
    STAGE_STMT;                                                                   \
    __builtin_amdgcn_sched_barrier(0);                                            \
    __builtin_amdgcn_s_barrier();                                                 \
    __builtin_amdgcn_sched_barrier(0);                                            \
    __builtin_amdgcn_s_setprio(1);                                                \
    acc[(MH)*4 + 0][0] = __builtin_amdgcn_mfma_f32_16x16x32_f16(a0_, bfr[0], acc[(MH)*4 + 0][0], 0, 0, 0); \
    acc[(MH)*4 + 0][1] = __builtin_amdgcn_mfma_f32_16x16x32_f16(a0_, bfr[1], acc[(MH)*4 + 0][1], 0, 0, 0); \
    acc[(MH)*4 + 0][2] = __builtin_amdgcn_mfma_f32_16x16x32_f16(a0_, bfr[2], acc[(MH)*4 + 0][2], 0, 0, 0); \
    acc[(MH)*4 + 0][3] = __builtin_amdgcn_mfma_f32_16x16x32_f16(a0_, bfr[3], acc[(MH)*4 + 0][3], 0, 0, 0); \
    acc[(MH)*4 + 1][0] = __builtin_amdgcn_mfma_f32_16x16x32_f16(a1_, bfr[0], acc[(MH)*4 + 1][0], 0, 0, 0); \
    acc[(MH)*4 + 1][1] = __builtin_amdgcn_mfma_f32_16x16x32_f16(a1_, bfr[1], acc[(MH)*4 + 1][1], 0, 0, 0); \
    acc[(MH)*4 + 1][2] = __builtin_amdgcn_mfma_f32_16x16x32_f16(a1_, bfr[2], acc[(MH)*4 + 1][2], 0, 0, 0); \
    acc[(MH)*4 + 1][3] = __builtin_amdgcn_mfma_f32_16x16x32_f16(a1_, bfr[3], acc[(MH)*4 + 1][3], 0, 0, 0); \
    acc[(MH)*4 + 2][0] = __builtin_amdgcn_mfma_f32_16x16x32_f16(a2_, bfr[0], acc[(MH)*4 + 2][0], 0, 0, 0); \
    acc[(MH)*4 + 2][1] = __builtin_amdgcn_mfma_f32_16x16x32_f16(a2_, bfr[1], acc[(MH)*4 + 2][1], 0, 0, 0); \
    acc[(MH)*4 + 2][2] = __builtin_amdgcn_mfma_f32_16x16x32_f16(a2_, bfr[2], acc[(MH)*4 + 2][2], 0, 0, 0); \
    acc[(MH)*4 + 2][3] = __builtin_amdgcn_mfma_f32_16x16x32_f16(a2_, bfr[3], acc[(MH)*4 + 2][3], 0, 0, 0); \
    acc[(MH)*4 + 3][0] = __builtin_amdgcn_mfma_f32_16x16x32_f16(a3_, bfr[0], acc[(MH)*4 + 3][0], 0, 0, 0); \
    acc[(MH)*4 + 3][1] = __builtin_amdgcn_mfma_f32_16x16x32_f16(a3_, bfr[1], acc[(MH)*4 + 3][1], 0, 0, 0); \
    acc[(MH)*4 + 3][2] = __builtin_amdgcn_mfma_f32_16x16x32_f16(a3_, bfr[2], acc[(MH)*4 + 3][2], 0, 0, 0); \
    acc[(MH)*4 + 3][3] = __builtin_amdgcn_mfma_f32_16x16x32_f16(a3_, bfr[3], acc[(MH)*4 + 3][3], 0, 0, 0); \
    __builtin_amdgcn_s_setprio(0);                                                \
    __builtin_amdgcn_sched_barrier(0);                                            \
    WAIT_STMT;                                                                    \
    __builtin_amdgcn_s_barrier();                                                 \
  }

  // prologue: tile 0 fully staged (8 loads); retire its K-half0 before P1(0).
  stage_half(0, 0);
  stage_half(0, 1);
  __builtin_amdgcn_s_waitcnt(0xF74);  // vmcnt(4)
  __builtin_amdgcn_s_barrier();

  // steady loop: tiles 0..14. Waits retire loads issued 3 phases earlier.
#pragma unroll 1
  for (int t = 0; t < 15; ++t) {
    int bo = (t & 1) * 16384;
    DO_PHASE(bo, 0, 0, true,  (stage_half(t + 1, 0)), ((void)0));
    DO_PHASE(bo, 1, 0, false, ((void)0), __builtin_amdgcn_s_waitcnt(0xF74));
    DO_PHASE(bo, 0, 1, true,  (stage_half(t + 1, 1)), ((void)0));
    DO_PHASE(bo, 1, 1, false, ((void)0), __builtin_amdgcn_s_waitcnt(0xF74));
  }
  // tail: tile 15 (no staging; drain remaining 4 loads before their reader)
  {
    int bo = 16384;
    DO_PHASE(bo, 0, 0, true,  ((void)0), ((void)0));
    DO_PHASE(bo, 1, 0, false, ((void)0), __builtin_amdgcn_s_waitcnt(0xF70));
    DO_PHASE(bo, 0, 1, true,  ((void)0), ((void)0));
    DO_PHASE(bo, 1, 1, false, ((void)0), ((void)0));
  }
#undef DO_PHASE

  // epilogue: 16x16 C/D layout: col = lane&15, row = (lane>>4)*4 + reg
  const float* cb = conf + (size_t)bz * N;
#pragma unroll
  for (int nf = 0; nf < 4; ++nf) {
    int gn = n0 + wn * 64 + nf * 16 + lr16;
    float cs = 0.03125f * cb[gn];
#pragma unroll
    for (int mf = 0; mf < 8; ++mf) {
      int gm = m0 + wm * 128 + mf * 16 + lq * 4;
#pragma unroll
      for (int rr = 0; rr < 4; ++rr)
        Sb[(size_t)(gm + rr) * N + gn] = (_Float16)(acc[mf][nf][rr] * cs);
    }
  }
}

// ------- softmax over X=8192 (fp16 S) + threshold + renorm + compact (x, w) -------
__global__ __launch_bounds__(256) void softmax_compact(
    const _Float16* __restrict__ S, unsigned* __restrict__ entries,
    int* __restrict__ counts) {
  const int X = 8192;
  size_t row = blockIdx.x;
  const half8* sr = (const half8*)(S + row * X);
  int t = threadIdx.x;
  int wave = t >> 6, lane = t & 63;
  __shared__ float sh[4];
  __shared__ int scnt;

  float v[32];
#pragma unroll
  for (int j = 0; j < 4; ++j) {
    half8 h = sr[t + j * 256];
#pragma unroll
    for (int c = 0; c < 8; ++c) v[j * 8 + c] = (float)h[c];
  }

  float m = -1e30f;
#pragma unroll
  for (int i = 0; i < 32; ++i) m = fmaxf(m, v[i]);
#pragma unroll
  for (int off = 1; off < 64; off <<= 1) m = fmaxf(m, __shfl_xor(m, off, 64));
  if (lane == 0) sh[wave] = m;
  __syncthreads();
  m = fmaxf(fmaxf(sh[0], sh[1]), fmaxf(sh[2], sh[3]));
  __syncthreads();

  float l = 0.f;
#pragma unroll
  for (int i = 0; i < 32; ++i) {
    v[i] = __expf(v[i] - m);
    l += v[i];
  }
#pragma unroll
  for (int off = 1; off < 64; off <<= 1) l += __shfl_xor(l, off, 64);
  if (lane == 0) sh[wave] = l;
  __syncthreads();
  l = sh[0] + sh[1] + sh[2] + sh[3];
  __syncthreads();

  float thr = 0.0005f * l;
  float ks = 0.f;
#pragma unroll
  for (int i = 0; i < 32; ++i) {
    v[i] = (v[i] >= thr) ? v[i] : 0.f;
    ks += v[i];
  }
#pragma unroll
  for (int off = 1; off < 64; off <<= 1) ks += __shfl_xor(ks, off, 64);
  if (lane == 0) sh[wave] = ks;
  __syncthreads();
  if (t == 0) scnt = 0;
  __syncthreads();
  ks = sh[0] + sh[1] + sh[2] + sh[3];

  float inv = 1.0f / ks;
  unsigned* er = entries + row * 2048;
#pragma unroll
  for (int j = 0; j < 4; ++j) {
#pragma unroll
    for (int c = 0; c < 8; ++c) {
      float val = v[j * 8 + c];
      if (val > 0.f) {
        int pos = atomicAdd(&scnt, 1);
        _Float16 h = (_Float16)(val * inv);
        unsigned short hb;
        __builtin_memcpy(&hb, &h, 2);
        er[pos] = ((unsigned)((t + j * 256) * 8 + c) << 16) | hb;
      }
    }
  }
  __syncthreads();
  if (t == 0) counts[row] = scnt;
}

__device__ __forceinline__ void acc4(float* a, unsigned w, float wt) {
  a[0] += wt * (float)(signed char)(w & 0xff);
  a[1] += wt * (float)(signed char)((w >> 8) & 0xff);
  a[2] += wt * (float)(signed char)((w >> 16) & 0xff);
  a[3] += wt * (float)(signed char)(w >> 24);
}

// --- sparse gather (int8 v): out[row] = feat[row] + sum w*scale[x]*v8[x] ---
// 512 threads = 8 entry-streams (one per wave) x 64 lanes x 16 B.
__global__ __launch_bounds__(512) void gather_pv_i8(
    const unsigned* __restrict__ entries, const int* __restrict__ counts,
    const char* __restrict__ v8, const float* __restrict__ vscale,
    const float* __restrict__ feat, float* __restrict__ out) {
  const int X = 8192, C = 1024;
  int row = blockIdx.x;  // b*1024 + p
  int b = row >> 10;
  int t = threadIdx.x;
  int s = t >> 6;         // stream = wave 0..7
  int lane = t & 63;
  int c = lane * 16;      // byte offset within v-row

  __shared__ unsigned se[2048];
  __shared__ float red[8][1028];

  int cnt = counts[row];
  const unsigned* er = entries + (size_t)row * 2048;
  for (int i = t; i < cnt; i += 512) se[i] = er[i];
  __syncthreads();

  const char* vb = v8 + (size_t)b * X * C;
  const float* sb = vscale + (size_t)b * X;
  float a[16];
#pragma unroll
  for (int i = 0; i < 16; ++i) a[i] = 0.f;

#pragma unroll 2
  for (int j = s; j < cnt; j += 8) {
    unsigned e = se[j];
    int x = e >> 16;
    float w = h2f((unsigned short)(e & 0xffff)) * sb[x];
    uint4 pv = *(const uint4*)(vb + (size_t)x * C + c);
    acc4(a + 0, pv.x, w);
    acc4(a + 4, pv.y, w);
    acc4(a + 8, pv.z, w);
    acc4(a + 12, pv.w, w);
  }
  float* rp = &red[s][c];
#pragma unroll
  for (int i = 0; i < 16; ++i) rp[i] = a[i];
  __syncthreads();

  int p = t * 2;
  float2 f = *(const float2*)(feat + (size_t)row * C + p);
  float o0 = f.x, o1 = f.y;
#pragma unroll
  for (int ss = 0; ss < 8; ++ss) {
    o0 += red[ss][p];
    o1 += red[ss][p + 1];
  }
  float2 o = {o0, o1};
  *(float2*)(out + (size_t)row * C + p) = o;
}

extern "C" void kernel_launch(void* const* d_in, const int* in_sizes, int n_in,
                              void* d_out, int out_size, void* d_ws, size_t ws_size,
                              hipStream_t stream) {
  const int B = 4, P = 1024, X = 8192, C = 1024;
  const float* feat  = (const float*)d_in[0];
  const float* mem_k = (const float*)d_in[1];
  const float* mem_v = (const float*)d_in[2];
  const float* mem_c = (const float*)d_in[3];  // [B,X,1] -> flat [B*X]
  const float* g_q = (const float*)d_in[5];
  const float* b_q = (const float*)d_in[6];
  const float* g_k = (const float*)d_in[7];
  const float* b_k = (const float*)d_in[8];
  const float* g_v = (const float*)d_in[9];
  const float* b_v = (const float*)d_in[10];

  char* ws = (char*)d_ws;
  const size_t MB = 1024 * 1024;
  _Float16* q16 = (_Float16*)(ws + 0);             // 8 MB   [B][P][C]
  _Float16* k16 = (_Float16*)(ws + 8 * MB);        // 64 MB  [B][X][C]
  _Float16* S   = (_Float16*)(ws + 72 * MB);       // 64 MB  [B][P][X]
  char*     v8  = (char*)(ws + 136 * MB);          // 32 MB  [B][X][C] int8
  float* vscale = (float*)(ws + 168 * MB);         // 128 KB [B*X]
  unsigned* entries = (unsigned*)(ws + 169 * MB);  // 32 MB  [B*P][2048]
  int*      counts  = (int*)(ws + 201 * MB);       // 16 KB  [B*P]

  ln_cast_f16<<<B * P, 256, 0, stream>>>(feat, g_q, b_q, q16);
  ln_cast_f16<<<B * X, 256, 0, stream>>>(mem_k, g_k, b_k, k16);
  ln_cast_i8<<<B * X, 256, 0, stream>>>(mem_v, g_v, b_v, v8, vscale);
  gemm_qk_8ph<<<dim3(X / 256, P / 256, B), 512, 0, stream>>>(q16, k16, S, mem_c);
  softmax_compact<<<B * P, 256, 0, stream>>>(S, entries, counts);
  gather_pv_i8<<<B * P, 512, 0, stream>>>(entries, counts, v8, vscale, feat,
                                          (float*)d_out);
}

// Round 4
// 501.055 us; speedup vs baseline: 1.0592x; 1.0592x over previous
//
#include <hip/hip_runtime.h>

typedef __attribute__((ext_vector_type(8))) _Float16 half8;
typedef __attribute__((ext_vector_type(4))) _Float16 half4v;
typedef __attribute__((ext_vector_type(4))) float f32x4;

__device__ __forceinline__ void gll16(const void* g, void* l) {
  __builtin_amdgcn_global_load_lds(
      (const __attribute__((address_space(1))) unsigned int*)g,
      (__attribute__((address_space(3))) unsigned int*)l, 16, 0, 0);
}

// ---- fused LayerNorm: one ROW PER WAVE, no barriers, no LDS ----
// tasks 0..4095        : feat -> q16 (fp16)
// tasks 4096..36863    : mem_k -> k16 (fp16)
// tasks 36864..69631   : mem_v -> v8 (int8 + per-row scale)
// 256 thr = 4 waves = 4 rows/block; segment boundaries are %4==0 so the
// segment branch is wave-uniform. 16 elems/lane, 6-step shuffle reduce.
__global__ __launch_bounds__(256) void ln_fused(
    const float* __restrict__ feat, const float* __restrict__ mem_k,
    const float* __restrict__ mem_v, const float* __restrict__ g_q,
    const float* __restrict__ b_q, const float* __restrict__ g_k,
    const float* __restrict__ b_k, const float* __restrict__ g_v,
    const float* __restrict__ b_v, _Float16* __restrict__ q16,
    _Float16* __restrict__ k16, char* __restrict__ v8,
    float* __restrict__ vscale) {
  const int C = 1024;
  int wave = threadIdx.x >> 6, lane = threadIdx.x & 63;
  int task = blockIdx.x * 4 + wave;

  const float *x, *g, *b;
  int mode;
  size_t row;
  if (task < 4096) {
    x = feat; g = g_q; b = b_q; mode = 0; row = task;
  } else if (task < 36864) {
    x = mem_k; g = g_k; b = b_k; mode = 1; row = task - 4096;
  } else {
    x = mem_v; g = g_v; b = b_v; mode = 2; row = task - 36864;
  }

  const float4* xr = (const float4*)(x + row * C);
  float4 v[4];
  float s = 0.f, s2 = 0.f;
#pragma unroll
  for (int j = 0; j < 4; ++j) {
    v[j] = xr[lane + j * 64];
    s += v[j].x + v[j].y + v[j].z + v[j].w;
    s2 += v[j].x * v[j].x + v[j].y * v[j].y + v[j].z * v[j].z + v[j].w * v[j].w;
  }
#pragma unroll
  for (int off = 1; off < 64; off <<= 1) {
    s += __shfl_xor(s, off, 64);
    s2 += __shfl_xor(s2, off, 64);
  }
  float mu = s * (1.0f / C);
  float var = s2 * (1.0f / C) - mu * mu;
  float rstd = rsqrtf(var + 1e-5f);

  float y[16];
#pragma unroll
  for (int j = 0; j < 4; ++j) {
    float4 gv = ((const float4*)g)[lane + j * 64];
    float4 bv = ((const float4*)b)[lane + j * 64];
    y[4 * j + 0] = (v[j].x - mu) * rstd * gv.x + bv.x;
    y[4 * j + 1] = (v[j].y - mu) * rstd * gv.y + bv.y;
    y[4 * j + 2] = (v[j].z - mu) * rstd * gv.z + bv.z;
    y[4 * j + 3] = (v[j].w - mu) * rstd * gv.w + bv.w;
  }

  if (mode < 2) {
    _Float16* yo = (mode == 0 ? q16 : k16) + row * C;
#pragma unroll
    for (int j = 0; j < 4; ++j) {
      half4v h;
      h.x = (_Float16)y[4 * j + 0];
      h.y = (_Float16)y[4 * j + 1];
      h.z = (_Float16)y[4 * j + 2];
      h.w = (_Float16)y[4 * j + 3];
      ((half4v*)yo)[lane + j * 64] = h;
    }
  } else {
    float mx = 0.f;
#pragma unroll
    for (int i = 0; i < 16; ++i) mx = fmaxf(mx, fabsf(y[i]));
#pragma unroll
    for (int off = 1; off < 64; off <<= 1) mx = fmaxf(mx, __shfl_xor(mx, off, 64));
    mx = fmaxf(mx, 1e-20f);
    float inv = 127.0f / mx;
    unsigned* yo = (unsigned*)(v8 + row * C);
#pragma unroll
    for (int j = 0; j < 4; ++j) {
      int q0 = (int)rintf(y[4 * j + 0] * inv), q1 = (int)rintf(y[4 * j + 1] * inv);
      int q2 = (int)rintf(y[4 * j + 2] * inv), q3 = (int)rintf(y[4 * j + 3] * inv);
      unsigned pk = ((unsigned)(q0 & 0xff)) | ((unsigned)(q1 & 0xff) << 8) |
                    ((unsigned)(q2 & 0xff) << 16) | ((unsigned)(q3 & 0xff) << 24);
      yo[lane + j * 64] = pk;
    }
    if (lane == 0) vscale[row] = mx * (1.0f / 127.0f);
  }
}

// -------- QK^T GEMM, 256x256 tile (round-1 verified, 136.5 us) --------
// 512 thr = 8 waves (2M x 4N), per-wave 128x64 out via mfma_f32_32x32x16_f16.
// BK=32, QUAD-buffered LDS (4 x 16KB per operand = 128 KiB), prefetch distance
// 3, counted s_waitcnt vmcnt(12) (never 0 in main loop), raw s_barrier,
// s_setprio(1) around each 8-MFMA cluster. LDS chunk-major [kc][row][8]:
// gll16-linear and bank-conflict-free (measured 0 conflicts).
__global__ __launch_bounds__(512, 2) void gemm_qk_256(
    const _Float16* __restrict__ A,   // [B][1024][1024] q16
    const _Float16* __restrict__ Bm,  // [B][8192][1024] k16
    _Float16* __restrict__ Sm,        // [B][1024][8192]
    const float* __restrict__ conf)   // [B][8192]
{
  const int N = 8192, K = 1024;
  int bz = blockIdx.z;
  const _Float16* Ab = A + (size_t)bz * 1024 * K;
  const _Float16* Bb = Bm + (size_t)bz * (size_t)N * K;
  _Float16* Sb = Sm + (size_t)bz * 1024 * N;

  __shared__ _Float16 lA[4 * 8192];
  __shared__ _Float16 lB[4 * 8192];

  int tid = threadIdx.x;
  int wave = tid >> 6, lane = tid & 63;
  int wm = wave >> 2, wn = wave & 3;   // 2 x 4 wave grid
  int lr = lane & 31, lk = lane >> 5;  // row-in-32 / k-chunk
  int m0 = blockIdx.y * 256, n0 = blockIdx.x * 256;

  typedef __attribute__((ext_vector_type(16))) float f32x16;
  f32x16 acc[4][2];
#pragma unroll
  for (int i = 0; i < 4; ++i)
#pragma unroll
    for (int j = 0; j < 2; ++j)
#pragma unroll
      for (int e = 0; e < 16; ++e) acc[i][j][e] = 0.f;

  int r = tid & 255, c0 = tid >> 8;
  const _Float16* gA = Ab + (size_t)(m0 + r) * K + c0 * 8;
  const _Float16* gB = Bb + (size_t)(n0 + r) * K + c0 * 8;
  int dA = c0 * 2048 + r * 8;  // halfs

  auto stage = [&](int t) {
    int bo = (t & 3) * 8192;
    const _Float16* ga = gA + t * 32;
    const _Float16* gb = gB + t * 32;
    gll16(ga, &lA[bo + dA]);
    gll16(ga + 16, &lA[bo + dA + 4096]);
    gll16(gb, &lB[bo + dA]);
    gll16(gb + 16, &lB[bo + dA + 4096]);
  };

  auto compute = [&](int bo) {
#pragma unroll
    for (int ks = 0; ks < 2; ++ks) {
      const _Float16* la = &lA[bo + (ks * 2 + lk) * 2048 + (wm * 128 + lr) * 8];
      const _Float16* lb = &lB[bo + (ks * 2 + lk) * 2048 + (wn * 64 + lr) * 8];
      half8 a0 = *(const half8*)(la);
      half8 a1 = *(const half8*)(la + 256);
      half8 a2 = *(const half8*)(la + 512);
      half8 a3 = *(const half8*)(la + 768);
      half8 b0 = *(const half8*)(lb);
      half8 b1 = *(const half8*)(lb + 256);
      __builtin_amdgcn_s_setprio(1);
      acc[0][0] = __builtin_amdgcn_mfma_f32_32x32x16_f16(a0, b0, acc[0][0], 0, 0, 0);
      acc[1][0] = __builtin_amdgcn_mfma_f32_32x32x16_f16(a1, b0, acc[1][0], 0, 0, 0);
      acc[2][0] = __builtin_amdgcn_mfma_f32_32x32x16_f16(a2, b0, acc[2][0], 0, 0, 0);
      acc[3][0] = __builtin_amdgcn_mfma_f32_32x32x16_f16(a3, b0, acc[3][0], 0, 0, 0);
      acc[0][1] = __builtin_amdgcn_mfma_f32_32x32x16_f16(a0, b1, acc[0][1], 0, 0, 0);
      acc[1][1] = __builtin_amdgcn_mfma_f32_32x32x16_f16(a1, b1, acc[1][1], 0, 0, 0);
      acc[2][1] = __builtin_amdgcn_mfma_f32_32x32x16_f16(a2, b1, acc[2][1], 0, 0, 0);
      acc[3][1] = __builtin_amdgcn_mfma_f32_32x32x16_f16(a3, b1, acc[3][1], 0, 0, 0);
      __builtin_amdgcn_s_setprio(0);
    }
  };

  stage(0);
  stage(1);
  stage(2);

#pragma unroll 4
  for (int kt = 0; kt < 29; ++kt) {
    stage(kt + 3);
    __builtin_amdgcn_s_waitcnt(0xF7C);  // vmcnt(12)
    __builtin_amdgcn_s_barrier();
    __builtin_amdgcn_sched_barrier(0);
    compute((kt & 3) * 8192);
    __builtin_amdgcn_sched_barrier(0);
    __builtin_amdgcn_s_barrier();
  }
  __builtin_amdgcn_s_waitcnt(0xF78);  // vmcnt(8)
  __builtin_amdgcn_s_barrier();
  __builtin_amdgcn_sched_barrier(0);
  compute(1 * 8192);
  __builtin_amdgcn_sched_barrier(0);
  __builtin_amdgcn_s_barrier();
  __builtin_amdgcn_s_waitcnt(0xF74);  // vmcnt(4)
  __builtin_amdgcn_s_barrier();
  __builtin_amdgcn_sched_barrier(0);
  compute(2 * 8192);
  __builtin_amdgcn_sched_barrier(0);
  __builtin_amdgcn_s_barrier();
  __builtin_amdgcn_s_waitcnt(0xF70);  // vmcnt(0)
  __builtin_amdgcn_s_barrier();
  __builtin_amdgcn_sched_barrier(0);
  compute(3 * 8192);

  // epilogue: 32x32 C/D layout: col = lane&31, row = (r&3) + 8*(r>>2) + 4*(lane>>5)
  const float* cb = conf + (size_t)bz * N;
#pragma unroll
  for (int nf = 0; nf < 2; ++nf) {
    int gn = n0 + wn * 64 + nf * 32 + lr;
    float cs = 0.03125f * cb[gn];
#pragma unroll
    for (int mf = 0; mf < 4; ++mf) {
      int gmb = m0 + wm * 128 + mf * 32 + 4 * lk;
#pragma unroll
      for (int rr = 0; rr < 16; ++rr) {
        int gm = gmb + (rr & 3) + 8 * (rr >> 2);
        Sb[(size_t)gm * N + gn] = (_Float16)(acc[mf][nf][rr] * cs);
      }
    }
  }
}

__device__ __forceinline__ void acc4(float* a, unsigned w, float wt) {
  a[0] += wt * (float)(signed char)(w & 0xff);
  a[1] += wt * (float)(signed char)((w >> 8) & 0xff);
  a[2] += wt * (float)(signed char)((w >> 16) & 0xff);
  a[3] += wt * (float)(signed char)(w >> 24);
}

// ---- fused softmax + threshold + renorm + compact(LDS) + sparse gather ----
// One block (512 thr) per output row. Softmax over X=8192 (16 elems/thread),
// compact surviving (x, w*vscale[x]) into LDS (w held in f32, scale pre-
// folded so the gather loop has no dependent scalar global load), then
// 8 wave-streams gather int8 v rows and reduce. out = feat + sum.
__global__ __launch_bounds__(512) void softmax_gather(
    const _Float16* __restrict__ S, const char* __restrict__ v8,
    const float* __restrict__ vscale, const float* __restrict__ feat,
    float* __restrict__ out) {
  const int X = 8192, C = 1024;
  int row = blockIdx.x;  // b*1024 + p
  int b = row >> 10;
  int t = threadIdx.x;
  int wave = t >> 6, lane = t & 63;

  __shared__ float sh[8];
  __shared__ int scnt;
  __shared__ unsigned short sx[2048];
  __shared__ float sw[2048];
  __shared__ float red[8][1028];

  const half8* sr = (const half8*)(S + (size_t)row * X);
  float v[16];
#pragma unroll
  for (int j = 0; j < 2; ++j) {
    half8 h = sr[t + j * 512];
#pragma unroll
    for (int c = 0; c < 8; ++c) v[j * 8 + c] = (float)h[c];
  }

  float m = -1e30f;
#pragma unroll
  for (int i = 0; i < 16; ++i) m = fmaxf(m, v[i]);
#pragma unroll
  for (int off = 1; off < 64; off <<= 1) m = fmaxf(m, __shfl_xor(m, off, 64));
  if (lane == 0) sh[wave] = m;
  __syncthreads();
  m = fmaxf(fmaxf(fmaxf(sh[0], sh[1]), fmaxf(sh[2], sh[3])),
            fmaxf(fmaxf(sh[4], sh[5]), fmaxf(sh[6], sh[7])));
  __syncthreads();

  float l = 0.f;
#pragma unroll
  for (int i = 0; i < 16; ++i) {
    v[i] = __expf(v[i] - m);
    l += v[i];
  }
#pragma unroll
  for (int off = 1; off < 64; off <<= 1) l += __shfl_xor(l, off, 64);
  if (lane == 0) sh[wave] = l;
  __syncthreads();
  l = sh[0] + sh[1] + sh[2] + sh[3] + sh[4] + sh[5] + sh[6] + sh[7];
  __syncthreads();

  float thr = 0.0005f * l;
  float ks = 0.f;
#pragma unroll
  for (int i = 0; i < 16; ++i) {
    v[i] = (v[i] >= thr) ? v[i] : 0.f;
    ks += v[i];
  }
#pragma unroll
  for (int off = 1; off < 64; off <<= 1) ks += __shfl_xor(ks, off, 64);
  if (lane == 0) sh[wave] = ks;
  if (t == 0) scnt = 0;
  __syncthreads();
  ks = sh[0] + sh[1] + sh[2] + sh[3] + sh[4] + sh[5] + sh[6] + sh[7];

  float inv = 1.0f / ks;
  const float* sb = vscale + (size_t)b * X;
#pragma unroll
  for (int j = 0; j < 2; ++j) {
#pragma unroll
    for (int c = 0; c < 8; ++c) {
      float val = v[j * 8 + c];
      if (val > 0.f) {
        int pos = atomicAdd(&scnt, 1);
        int x = (t + j * 512) * 8 + c;
        sx[pos] = (unsigned short)x;
        sw[pos] = val * inv * sb[x];
      }
    }
  }
  __syncthreads();
  int cnt = scnt;

  const char* vb = v8 + (size_t)b * X * C;
  int cby = lane * 16;  // byte offset within v-row; also float index into red
  float a[16];
#pragma unroll
  for (int i = 0; i < 16; ++i) a[i] = 0.f;

#pragma unroll 2
  for (int j = wave; j < cnt; j += 8) {
    int x = sx[j];
    float w = sw[j];
    uint4 pv = *(const uint4*)(vb + (size_t)x * C + cby);
    acc4(a + 0, pv.x, w);
    acc4(a + 4, pv.y, w);
    acc4(a + 8, pv.z, w);
    acc4(a + 12, pv.w, w);
  }
  float* rp = &red[wave][cby];
#pragma unroll
  for (int i = 0; i < 16; ++i) rp[i] = a[i];
  __syncthreads();

  int p = t * 2;
  float2 f = *(const float2*)(feat + (size_t)row * C + p);
  float o0 = f.x, o1 = f.y;
#pragma unroll
  for (int ss = 0; ss < 8; ++ss) {
    o0 += red[ss][p];
    o1 += red[ss][p + 1];
  }
  float2 o = {o0, o1};
  *(float2*)(out + (size_t)row * C + p) = o;
}

extern "C" void kernel_launch(void* const* d_in, const int* in_sizes, int n_in,
                              void* d_out, int out_size, void* d_ws, size_t ws_size,
                              hipStream_t stream) {
  const int B = 4, P = 1024, X = 8192, C = 1024;
  const float* feat  = (const float*)d_in[0];
  const float* mem_k = (const float*)d_in[1];
  const float* mem_v = (const float*)d_in[2];
  const float* mem_c = (const float*)d_in[3];  // [B,X,1] -> flat [B*X]
  const float* g_q = (const float*)d_in[5];
  const float* b_q = (const float*)d_in[6];
  const float* g_k = (const float*)d_in[7];
  const float* b_k = (const float*)d_in[8];
  const float* g_v = (const float*)d_in[9];
  const float* b_v = (const float*)d_in[10];

  char* ws = (char*)d_ws;
  const size_t MB = 1024 * 1024;
  _Float16* q16 = (_Float16*)(ws + 0);             // 8 MB   [B][P][C]
  _Float16* k16 = (_Float16*)(ws + 8 * MB);        // 64 MB  [B][X][C]
  _Float16* S   = (_Float16*)(ws + 72 * MB);       // 64 MB  [B][P][X]
  char*     v8  = (char*)(ws + 136 * MB);          // 32 MB  [B][X][C] int8
  float* vscale = (float*)(ws + 168 * MB);         // 128 KB [B*X]

  // 69632 row-tasks (4096 q + 32768 k + 32768 v), 4 waves/block
  ln_fused<<<(4096 + 32768 + 32768) / 4, 256, 0, stream>>>(
      feat, mem_k, mem_v, g_q, b_q, g_k, b_k, g_v, b_v, q16, k16, v8, vscale);
  gemm_qk_256<<<dim3(X / 256, P / 256, B), 512, 0, stream>>>(q16, k16, S, mem_c);
  softmax_gather<<<B * P, 512, 0, stream>>>(S, v8, vscale, feat, (float*)d_out);
}